// Round 13
// baseline (175.114 us; speedup 1.0000x reference)
//
#include <hip/hip_runtime.h>

#define B_ 2
#define T_ 2048
#define C_ 1024
#define H_ 16
#define DH_ 64

typedef __attribute__((ext_vector_type(8))) _Float16 half8;  // 8 f16 (4 VGPRs)
typedef __attribute__((ext_vector_type(2))) __fp16 fp16x2;   // cvt_pkrtz result type
typedef __attribute__((ext_vector_type(4))) float f32x4;

__device__ __forceinline__ unsigned short f2h(float f) {
    union { _Float16 h; unsigned short u; } cv; cv.h = (_Float16)f; return cv.u;
}
__device__ __forceinline__ unsigned pk2(float a, float b) {
    union { fp16x2 h; unsigned u; } cv;
    cv.h = __builtin_amdgcn_cvt_pkrtz(a, b);
    return cv.u;
}

__device__ __forceinline__ void gll16(const void* g, void* l) {
    __builtin_amdgcn_global_load_lds(
        (const __attribute__((address_space(1))) void*)g,
        (__attribute__((address_space(3))) void*)l, 16, 0, 0);
}

// ---------------------------------------------------------------------------
// Prep (single launch): blocks [0,2048): x fp32->fp16 (+mask vec in block 0);
// blocks [2048, 5120): W transpose+convert -> Wt[z] (fp16 [N][K]).
// ---------------------------------------------------------------------------
__global__ __launch_bounds__(256) void prep_kernel(
    const float* __restrict__ x, unsigned short* __restrict__ xf,
    const int* __restrict__ mask, unsigned short* __restrict__ mb,
    const float* __restrict__ Wq, const float* __restrict__ Wk,
    const float* __restrict__ Wv, unsigned short* __restrict__ wt)
{
    __shared__ float tile[32][33];
    const int tid = threadIdx.x;

    if (blockIdx.x < 2048) {
        const size_t idx8 = ((size_t)blockIdx.x * 256 + tid) * 8;
        float4 v0 = *(const float4*)(x + idx8);
        float4 v1 = *(const float4*)(x + idx8 + 4);
        float f[8] = {v0.x, v0.y, v0.z, v0.w, v1.x, v1.y, v1.z, v1.w};
        unsigned short h[8];
#pragma unroll
        for (int i = 0; i < 8; i++) h[i] = f2h(f[i]);
        *(uint4*)(xf + idx8) = *(const uint4*)h;

        if (blockIdx.x == 0) {
#pragma unroll
            for (int j = 0; j < 16; j++) {
                int i = tid * 16 + j;               // covers B_*T_ = 4096
                mb[i] = (mask[i] != 0) ? (unsigned short)0x3C00 : (unsigned short)0;
            }
        }
    } else {
        const int idx = blockIdx.x - 2048;
        const int z   = idx >> 10;
        const int rem = idx & 1023;
        const int n0  = (rem & 31) * 32;
        const int k0  = (rem >> 5) * 32;
        const float* __restrict__ W = (z == 0) ? Wq : (z == 1) ? Wk : Wv;
        unsigned short* __restrict__ wtz = wt + (size_t)z * C_ * C_;
        const int tx = tid & 31;
        const int ty = tid >> 5;                    // 0..7
#pragma unroll
        for (int j = 0; j < 4; j++)
            tile[ty + j * 8][tx] = W[(size_t)(k0 + ty + j * 8) * C_ + n0 + tx];
        __syncthreads();
#pragma unroll
        for (int j = 0; j < 4; j++)
            wtz[(size_t)(n0 + ty + j * 8) * C_ + k0 + tx] = f2h(tile[tx][ty + j * 8]);
    }
}

// ---------------------------------------------------------------------------
// Fused QKV GEMM: ONE block computes q,k,v for its 128-tok x 128-col tile.
// X staged once per iter + 3 W tiles (64 KB LDS, single-buffer m97 style).
// Per wave-iter: 8 af + 24 bf ds_read_b128, 96 MFMA (3:1). Grid 256 = 1/CU.
// q/k: A=X,B=W -> D[tok][col].  v: A=W,B=X -> D[col][tok] (transposed out).
// Q pre-scaled by log2(e)/8; V mask-zeroed.
// ---------------------------------------------------------------------------
__global__ __launch_bounds__(256, 1) void qkv_fused_kernel(
    const unsigned short* __restrict__ xf, const unsigned short* __restrict__ wt,
    const float* __restrict__ bq, const float* __restrict__ bk,
    const float* __restrict__ bv, const int* __restrict__ maskp,
    unsigned short* __restrict__ qb, unsigned short* __restrict__ kb,
    unsigned short* __restrict__ vt)
{
    __shared__ unsigned short sX[128 * 64];       // 16 KB
    __shared__ unsigned short sW[3 * 128 * 64];   // 48 KB

    const int tok0 = blockIdx.x * 128;
    const int col0 = blockIdx.y * 128;
    const int wv    = threadIdx.x >> 6;
    const int lane  = threadIdx.x & 63;
    const int l15   = lane & 15;
    const int quad  = lane >> 4;
    const int l7    = l15 & 7;
    const int wm    = wv >> 1;       // token half (64)
    const int wn    = wv & 1;        // col half (64)
    const int lrow8 = lane >> 3;
    const int gch   = (lane & 7) ^ lrow8;

    f32x4 accq[4][4], acck[4][4], accv[4][4];
#pragma unroll
    for (int i = 0; i < 4; i++)
#pragma unroll
        for (int j = 0; j < 4; j++) {
            accq[i][j] = (f32x4){0.f, 0.f, 0.f, 0.f};
            acck[i][j] = (f32x4){0.f, 0.f, 0.f, 0.f};
            accv[i][j] = (f32x4){0.f, 0.f, 0.f, 0.f};
        }

    int aoff[4][2], boff[4][2];
#pragma unroll
    for (int i = 0; i < 4; i++)
#pragma unroll
        for (int s = 0; s < 2; s++) {
            aoff[i][s] = (wm * 64 + i * 16 + l15) * 64 + (((s * 4 + quad) ^ l7) * 8);
            boff[i][s] = (wn * 64 + i * 16 + l15) * 64 + (((s * 4 + quad) ^ l7) * 8);
        }

    for (int k0 = 0; k0 < C_; k0 += 64) {
        __syncthreads();
        // stage 64 KB: 64 chunks of (8 rows x 128 B); wave wv takes c = wv + 4s
#pragma unroll
        for (int s = 0; s < 16; ++s) {
            int c = (s << 2) + wv;
            if (c < 16) {
                int r0 = c << 3;
                gll16(xf + (size_t)(tok0 + r0 + lrow8) * C_ + k0 + gch * 8,
                      sX + r0 * 64);
            } else {
                int w  = c - 16;
                int z  = w >> 4;
                int r0 = (w & 15) << 3;
                gll16(wt + (size_t)z * C_ * C_
                         + (size_t)(col0 + r0 + lrow8) * C_ + k0 + gch * 8,
                      sW + z * 8192 + r0 * 64);
            }
        }
        __syncthreads();

        half8 af[4][2];
#pragma unroll
        for (int i = 0; i < 4; i++)
#pragma unroll
            for (int s = 0; s < 2; s++)
                af[i][s] = *(const half8*)&sX[aoff[i][s]];

        // ---- z=0 (q): D[tok][col] ----
#pragma unroll
        for (int j = 0; j < 4; j++) {
            half8 bw0 = *(const half8*)&sW[boff[j][0]];
            half8 bw1 = *(const half8*)&sW[boff[j][1]];
#pragma unroll
            for (int i = 0; i < 4; i++) {
                accq[i][j] = __builtin_amdgcn_mfma_f32_16x16x32_f16(af[i][0], bw0, accq[i][j], 0, 0, 0);
                accq[i][j] = __builtin_amdgcn_mfma_f32_16x16x32_f16(af[i][1], bw1, accq[i][j], 0, 0, 0);
            }
        }
        // ---- z=1 (k) ----
#pragma unroll
        for (int j = 0; j < 4; j++) {
            half8 bw0 = *(const half8*)&sW[8192 + boff[j][0]];
            half8 bw1 = *(const half8*)&sW[8192 + boff[j][1]];
#pragma unroll
            for (int i = 0; i < 4; i++) {
                acck[i][j] = __builtin_amdgcn_mfma_f32_16x16x32_f16(af[i][0], bw0, acck[i][j], 0, 0, 0);
                acck[i][j] = __builtin_amdgcn_mfma_f32_16x16x32_f16(af[i][1], bw1, acck[i][j], 0, 0, 0);
            }
        }
        // ---- z=2 (v): operand swap, D[col][tok] ----
#pragma unroll
        for (int i = 0; i < 4; i++) {
            half8 aw0 = *(const half8*)&sW[16384 + boff[i][0]];
            half8 aw1 = *(const half8*)&sW[16384 + boff[i][1]];
#pragma unroll
            for (int j = 0; j < 4; j++) {
                accv[i][j] = __builtin_amdgcn_mfma_f32_16x16x32_f16(aw0, af[j][0], accv[i][j], 0, 0, 0);
                accv[i][j] = __builtin_amdgcn_mfma_f32_16x16x32_f16(aw1, af[j][1], accv[i][j], 0, 0, 0);
            }
        }
    }

    // ---- epilogue q/k: D row = tok (wm range), col = wn range ----
#pragma unroll
    for (int j = 0; j < 4; j++) {
        int col = col0 + wn * 64 + j * 16 + l15;
        int h = col >> 6, d = col & 63;
        float bsq = bq[col];
        float bsk = bk[col];
#pragma unroll
        for (int i = 0; i < 4; i++) {
#pragma unroll
            for (int r = 0; r < 4; r++) {
                int tok = tok0 + wm * 64 + i * 16 + quad * 4 + r;
                int bidx = tok >> 11, t = tok & (T_ - 1);
                size_t base = ((size_t)(bidx * H_ + h) * T_ + t) * DH_ + d;
                qb[base] = f2h((accq[i][j][r] + bsq) * 0.18033688011112042f);
                kb[base] = f2h(acck[i][j][r] + bsk);
            }
        }
    }
    // ---- epilogue v: D row = col (wn range), col = tok (wm range) ----
    {
        float mv4[4]; int bidx4[4], t4[4];
#pragma unroll
        for (int j = 0; j < 4; j++) {
            int tok = tok0 + wm * 64 + j * 16 + l15;
            bidx4[j] = tok >> 11; t4[j] = tok & (T_ - 1);
            mv4[j] = (maskp[bidx4[j] * T_ + t4[j]] != 0) ? 1.f : 0.f;
        }
#pragma unroll
        for (int i = 0; i < 4; i++) {
#pragma unroll
            for (int r = 0; r < 4; r++) {
                int col = col0 + wn * 64 + i * 16 + quad * 4 + r;
                int h = col >> 6, d = col & 63;
                float bs = bv[col];
#pragma unroll
                for (int j = 0; j < 4; j++) {
                    vt[((size_t)(bidx4[j] * H_ + h) * DH_ + d) * T_ + t4[j]] =
                        f2h((accv[i][j][r] + bs) * mv4[j]);
                }
            }
        }
    }
}

// ---------------------------------------------------------------------------
// Attention: R12 verbatim (best measured: 61.2 us).
// ---------------------------------------------------------------------------
__global__ __launch_bounds__(256) void attn_mfma_kernel(
    const unsigned short* __restrict__ qb,  // [32][2048][64] f16 (pre-scaled)
    const unsigned short* __restrict__ kb,  // [32][2048][64] f16
    const unsigned short* __restrict__ vt,  // [32][64][2048] f16 (mask-zeroed)
    const int* __restrict__ mask,           // [2][2048]
    const unsigned short* __restrict__ mb,  // [2][2048] f16 {0,1}
    float* __restrict__ out)                // [2][2048][1024]
{
    __shared__ unsigned short Ks[2][64 * 64];
    __shared__ unsigned short Vs[2][64 * 64];
    __shared__ unsigned short Ps[4][2][16 * 64];  // per-wave per-qt P buffers

    const int bh   = blockIdx.x;            // bh-major: same head -> same XCD
    const int b    = bh >> 4;
    const int h    = bh & 15;
    const int wv   = threadIdx.x >> 6;
    const int lane = threadIdx.x & 63;
    const int l15  = lane & 15;
    const int quad = lane >> 4;
    const int l7   = l15 & 7;
    const int q0w  = blockIdx.y * 128 + wv * 32;

    const unsigned short* kbh = kb + (size_t)bh * T_ * DH_;
    const unsigned short* vbh = vt + (size_t)bh * DH_ * T_;
    const unsigned short* mbb = mb + b * T_;
    const int* __restrict__ mrow = mask + b * T_;

    half8 qf[2][2];
#pragma unroll
    for (int qt = 0; qt < 2; ++qt)
#pragma unroll
        for (int c = 0; c < 2; ++c)
            qf[qt][c] = *(const half8*)(qb + ((size_t)bh * T_ + q0w + qt * 16 + l15) * DH_
                                        + c * 32 + quad * 8);

    f32x4 o[2][4];
#pragma unroll
    for (int qt = 0; qt < 2; ++qt)
#pragma unroll
        for (int n = 0; n < 4; ++n) o[qt][n] = (f32x4){0.f, 0.f, 0.f, 0.f};
    f32x4 lacc[2];
    lacc[0] = (f32x4){0.f, 0.f, 0.f, 0.f};
    lacc[1] = (f32x4){0.f, 0.f, 0.f, 0.f};

    const int lrow = lane >> 3;
    const int gch  = (lane & 7) ^ lrow;

#pragma unroll
    for (int s = 0; s < 4; ++s) {
        int j  = (wv << 2) + s;
        int rb = j & 7;
        if (j < 8) gll16(kbh + (size_t)(rb * 8 + lrow) * DH_ + gch * 8, &Ks[0][rb * 512]);
        else       gll16(vbh + (size_t)(rb * 8 + lrow) * T_  + gch * 8, &Vs[0][rb * 512]);
    }

    for (int kt = 0; kt < 32; ++kt) {
        const int cur   = kt & 1;
        const int kbase = kt * 64;
        __syncthreads();

        if (kt < 31) {
            const int nb = kbase + 64;
#pragma unroll
            for (int s = 0; s < 4; ++s) {
                int j  = (wv << 2) + s;
                int rb = j & 7;
                if (j < 8) gll16(kbh + (size_t)(nb + rb * 8 + lrow) * DH_ + gch * 8,
                                 &Ks[cur ^ 1][rb * 512]);
                else       gll16(vbh + (size_t)(rb * 8 + lrow) * T_ + nb + gch * 8,
                                 &Vs[cur ^ 1][rb * 512]);
            }
        }

        const unsigned short* Kc = &Ks[cur][0];
        const unsigned short* Vc = &Vs[cur][0];

        half8 kf[4][2], vf[4][2];
#pragma unroll
        for (int ktile = 0; ktile < 4; ++ktile)
#pragma unroll
            for (int c = 0; c < 2; ++c) {
                kf[ktile][c] = *(const half8*)(Kc + (ktile * 16 + l15) * 64
                                               + (((c * 4 + quad) ^ l7) * 8));
                vf[ktile][c] = *(const half8*)(Vc + (ktile * 16 + l15) * 64
                                               + (((c * 4 + quad) ^ l7) * 8));
            }

        half8 bmf[2];
#pragma unroll
        for (int kc = 0; kc < 2; ++kc) {
            half8 mv = *(const half8*)(mbb + kbase + kc * 32 + quad * 8);
            bmf[kc] = (l15 == 0) ? mv : (half8)0;
        }

        // ---- Phase 1: S^T + exp for BOTH q-tiles ----
#pragma unroll
        for (int qt = 0; qt < 2; ++qt) {
            unsigned short* Pq = &Ps[wv][qt][0];
#pragma unroll
            for (int ktile = 0; ktile < 4; ++ktile) {
                f32x4 st = (f32x4){0.f, 0.f, 0.f, 0.f};
                st = __builtin_amdgcn_mfma_f32_16x16x32_f16(kf[ktile][0], qf[qt][0], st, 0, 0, 0);
                st = __builtin_amdgcn_mfma_f32_16x16x32_f16(kf[ktile][1], qf[qt][1], st, 0, 0, 0);
                uint2 pk;
                pk.x = pk2(__builtin_amdgcn_exp2f(st[0]), __builtin_amdgcn_exp2f(st[1]));
                pk.y = pk2(__builtin_amdgcn_exp2f(st[2]), __builtin_amdgcn_exp2f(st[3]));
                *(uint2*)(Pq + l15 * 64 + (((ktile * 2 + (quad >> 1)) ^ l7) * 8)
                          + (quad & 1) * 4) = pk;
            }
        }

        // ---- Phase 2: P-reads + l + PV ----
#pragma unroll
        for (int qt = 0; qt < 2; ++qt) {
            const unsigned short* Pq = &Ps[wv][qt][0];
            half8 pf[2];
#pragma unroll
            for (int kc = 0; kc < 2; ++kc)
                pf[kc] = *(const half8*)(Pq + l15 * 64 + (((kc * 4 + quad) ^ l7) * 8));

            lacc[qt] = __builtin_amdgcn_mfma_f32_16x16x32_f16(pf[0], bmf[0], lacc[qt], 0, 0, 0);
            lacc[qt] = __builtin_amdgcn_mfma_f32_16x16x32_f16(pf[1], bmf[1], lacc[qt], 0, 0, 0);

#pragma unroll
            for (int n = 0; n < 4; ++n) {
#pragma unroll
                for (int kc = 0; kc < 2; ++kc)
                    o[qt][n] = __builtin_amdgcn_mfma_f32_16x16x32_f16(
                        pf[kc], vf[n][kc], o[qt][n], 0, 0, 0);
            }
        }
    }

#pragma unroll
    for (int qt = 0; qt < 2; ++qt) {
#pragma unroll
        for (int r = 0; r < 4; ++r) {
            float lv = __shfl(lacc[qt][r], quad << 4, 64);
            int q = q0w + qt * 16 + quad * 4 + r;
            float iv = (mrow[q] != 0 && lv > 0.f) ? (1.0f / lv) : 0.f;
            float* orow = out + ((size_t)(b * T_ + q)) * C_ + h * DH_;
#pragma unroll
            for (int n = 0; n < 4; ++n)
                orow[n * 16 + l15] = o[qt][n][r] * iv;
        }
    }
}

// ---------------------------------------------------------------------------
extern "C" void kernel_launch(void* const* d_in, const int* in_sizes, int n_in,
                              void* d_out, int out_size, void* d_ws, size_t ws_size,
                              hipStream_t stream)
{
    (void)in_sizes; (void)n_in; (void)out_size; (void)ws_size;
    const float* x  = (const float*)d_in[0];
    const float* Wq = (const float*)d_in[1];
    const float* bq = (const float*)d_in[2];
    const float* Wk = (const float*)d_in[3];
    const float* bk = (const float*)d_in[4];
    const float* Wv = (const float*)d_in[5];
    const float* bv = (const float*)d_in[6];
    const int* mask = (const int*)d_in[7];
    float* out = (float*)d_out;

    const size_t NX = (size_t)B_ * T_ * C_;          // 4 Mi elements
    unsigned short* xf = (unsigned short*)d_ws;       // 8 MB fp16 x
    unsigned short* wt = xf + NX;                     // 6 MB fp16 W^T x3
    unsigned short* qb = wt + (size_t)3 * C_ * C_;    // 8 MB (pre-scaled q)
    unsigned short* kb = qb + NX;                     // 8 MB
    unsigned short* vt = kb + NX;                     // 8 MB
    unsigned short* mb = vt + NX;                     // 8 KB

    prep_kernel<<<5120, 256, 0, stream>>>(x, xf, mask, mb, Wq, Wk, Wv, wt);
    qkv_fused_kernel<<<dim3(32, 8), 256, 0, stream>>>(
        xf, wt, bq, bk, bv, mask, qb, kb, vt);
    attn_mfma_kernel<<<dim3(32, 16), 256, 0, stream>>>(qb, kb, vt, mask, mb, out);
}

// Round 14
// 168.288 us; speedup vs baseline: 1.0406x; 1.0406x over previous
//
#include <hip/hip_runtime.h>

#define B_ 2
#define T_ 2048
#define C_ 1024
#define H_ 16
#define DH_ 64

typedef __attribute__((ext_vector_type(8))) _Float16 half8;  // 8 f16 (4 VGPRs)
typedef __attribute__((ext_vector_type(4))) _Float16 half4;  // 4 f16 (2 VGPRs)
typedef __attribute__((ext_vector_type(2))) __fp16 fp16x2;   // cvt_pkrtz result type
typedef __attribute__((ext_vector_type(4))) float f32x4;

__device__ __forceinline__ unsigned short f2h(float f) {
    union { _Float16 h; unsigned short u; } cv; cv.h = (_Float16)f; return cv.u;
}
__device__ __forceinline__ unsigned pk2(float a, float b) {
    union { fp16x2 h; unsigned u; } cv;
    cv.h = __builtin_amdgcn_cvt_pkrtz(a, b);
    return cv.u;
}

__device__ __forceinline__ void gll16(const void* g, void* l) {
    __builtin_amdgcn_global_load_lds(
        (const __attribute__((address_space(1))) void*)g,
        (__attribute__((address_space(3))) void*)l, 16, 0, 0);
}

// ---------------------------------------------------------------------------
// Prep (single launch): blocks [0,2048): x fp32->fp16 (+mask vec in block 0);
// blocks [2048, 5120): W transpose+convert -> Wt[z] (fp16 [N][K]).
// ---------------------------------------------------------------------------
__global__ __launch_bounds__(256) void prep_kernel(
    const float* __restrict__ x, unsigned short* __restrict__ xf,
    const int* __restrict__ mask, unsigned short* __restrict__ mb,
    const float* __restrict__ Wq, const float* __restrict__ Wk,
    const float* __restrict__ Wv, unsigned short* __restrict__ wt)
{
    __shared__ float tile[32][33];
    const int tid = threadIdx.x;

    if (blockIdx.x < 2048) {
        const size_t idx8 = ((size_t)blockIdx.x * 256 + tid) * 8;
        float4 v0 = *(const float4*)(x + idx8);
        float4 v1 = *(const float4*)(x + idx8 + 4);
        float f[8] = {v0.x, v0.y, v0.z, v0.w, v1.x, v1.y, v1.z, v1.w};
        unsigned short h[8];
#pragma unroll
        for (int i = 0; i < 8; i++) h[i] = f2h(f[i]);
        *(uint4*)(xf + idx8) = *(const uint4*)h;

        if (blockIdx.x == 0) {
#pragma unroll
            for (int j = 0; j < 16; j++) {
                int i = tid * 16 + j;               // covers B_*T_ = 4096
                mb[i] = (mask[i] != 0) ? (unsigned short)0x3C00 : (unsigned short)0;
            }
        }
    } else {
        const int idx = blockIdx.x - 2048;
        const int z   = idx >> 10;
        const int rem = idx & 1023;
        const int n0  = (rem & 31) * 32;
        const int k0  = (rem >> 5) * 32;
        const float* __restrict__ W = (z == 0) ? Wq : (z == 1) ? Wk : Wv;
        unsigned short* __restrict__ wtz = wt + (size_t)z * C_ * C_;
        const int tx = tid & 31;
        const int ty = tid >> 5;                    // 0..7
#pragma unroll
        for (int j = 0; j < 4; j++)
            tile[ty + j * 8][tx] = W[(size_t)(k0 + ty + j * 8) * C_ + n0 + tx];
        __syncthreads();
#pragma unroll
        for (int j = 0; j < 4; j++)
            wtz[(size_t)(n0 + ty + j * 8) * C_ + k0 + tx] = f2h(tile[tx][ty + j * 8]);
    }
}

// ---------------------------------------------------------------------------
// QKV projection (R12 structure — best measured total). z-grid, 3 blocks/CU.
// Q pre-scaled by log2(e)/8; V transposed + mask-zeroed.
// ---------------------------------------------------------------------------
__global__ __launch_bounds__(256) void qkv_mfma_kernel(
    const unsigned short* __restrict__ xf, const unsigned short* __restrict__ wt,
    const float* __restrict__ bq, const float* __restrict__ bk,
    const float* __restrict__ bv, const int* __restrict__ maskp,
    unsigned short* __restrict__ qb, unsigned short* __restrict__ kb,
    unsigned short* __restrict__ vt)
{
    __shared__ unsigned short sX[128 * 64];
    __shared__ unsigned short sW[128 * 64];

    const int z = blockIdx.z;
    const float* __restrict__ bias = (z == 0) ? bq : (z == 1) ? bk : bv;
    const unsigned short* __restrict__ wtz = wt + (size_t)z * C_ * C_;

    const int tok0 = blockIdx.x * 128;
    const int col0 = blockIdx.y * 128;
    const int wv    = threadIdx.x >> 6;
    const int lane  = threadIdx.x & 63;
    const int l15   = lane & 15;
    const int quad  = lane >> 4;
    const int l7    = l15 & 7;
    const int wm    = wv >> 1;
    const int wn    = wv & 1;
    const int lrow8 = lane >> 3;
    const int gch   = (lane & 7) ^ lrow8;

    f32x4 acc[4][4];
#pragma unroll
    for (int i = 0; i < 4; i++)
#pragma unroll
        for (int j = 0; j < 4; j++) acc[i][j] = (f32x4){0.f, 0.f, 0.f, 0.f};

    int aoff[4][2], boff[4][2];
#pragma unroll
    for (int i = 0; i < 4; i++)
#pragma unroll
        for (int s = 0; s < 2; s++) {
            aoff[i][s] = (wm * 64 + i * 16 + l15) * 64 + (((s * 4 + quad) ^ l7) * 8);
            boff[i][s] = (wn * 64 + i * 16 + l15) * 64 + (((s * 4 + quad) ^ l7) * 8);
        }

    const unsigned short* Abuf = (z < 2) ? sX : sW;
    const unsigned short* Bbuf = (z < 2) ? sW : sX;

    for (int k0 = 0; k0 < C_; k0 += 64) {
        __syncthreads();
#pragma unroll
        for (int s = 0; s < 8; ++s) {
            int g    = (s << 2) + wv;
            int tsel = g >> 4;
            int r0   = (g & 15) << 3;
            const unsigned short* src = tsel ? wtz : xf;
            unsigned short*       dst = tsel ? sW  : sX;
            int rowg = tsel ? col0 : tok0;
            gll16(src + (size_t)(rowg + r0 + lrow8) * C_ + k0 + gch * 8,
                  dst + r0 * 64);
        }
        __syncthreads();

        half8 af[4][2], bf_[4][2];
#pragma unroll
        for (int i = 0; i < 4; i++)
#pragma unroll
            for (int s = 0; s < 2; s++) {
                af[i][s]  = *(const half8*)&Abuf[aoff[i][s]];
                bf_[i][s] = *(const half8*)&Bbuf[boff[i][s]];
            }
#pragma unroll
        for (int s = 0; s < 2; s++)
#pragma unroll
            for (int j = 0; j < 4; j++)
#pragma unroll
                for (int i = 0; i < 4; i++)
                    acc[i][j] = __builtin_amdgcn_mfma_f32_16x16x32_f16(
                        af[i][s], bf_[j][s], acc[i][j], 0, 0, 0);
    }

    if (z == 0) {
#pragma unroll
        for (int j = 0; j < 4; j++) {
            int col = col0 + wn * 64 + j * 16 + l15;
            int h = col >> 6, d = col & 63;
            float bs = bias[col];
#pragma unroll
            for (int i = 0; i < 4; i++) {
#pragma unroll
                for (int r = 0; r < 4; r++) {
                    int tok = tok0 + wm * 64 + i * 16 + quad * 4 + r;
                    int bidx = tok >> 11, t = tok & (T_ - 1);
                    qb[((size_t)(bidx * H_ + h) * T_ + t) * DH_ + d] =
                        f2h((acc[i][j][r] + bs) * 0.18033688011112042f);
                }
            }
        }
    } else if (z == 1) {
#pragma unroll
        for (int j = 0; j < 4; j++) {
            int col = col0 + wn * 64 + j * 16 + l15;
            int h = col >> 6, d = col & 63;
            float bs = bias[col];
#pragma unroll
            for (int i = 0; i < 4; i++) {
#pragma unroll
                for (int r = 0; r < 4; r++) {
                    int tok = tok0 + wm * 64 + i * 16 + quad * 4 + r;
                    int bidx = tok >> 11, t = tok & (T_ - 1);
                    kb[((size_t)(bidx * H_ + h) * T_ + t) * DH_ + d] =
                        f2h(acc[i][j][r] + bs);
                }
            }
        }
    } else {
        float mv4[4]; int bidx4[4], t4[4];
#pragma unroll
        for (int j = 0; j < 4; j++) {
            int tok = tok0 + wn * 64 + j * 16 + l15;
            bidx4[j] = tok >> 11; t4[j] = tok & (T_ - 1);
            mv4[j] = (maskp[bidx4[j] * T_ + t4[j]] != 0) ? 1.f : 0.f;
        }
#pragma unroll
        for (int i = 0; i < 4; i++) {
#pragma unroll
            for (int r = 0; r < 4; r++) {
                int col = col0 + wm * 64 + i * 16 + quad * 4 + r;
                int h = col >> 6, d = col & 63;
                float bs = bias[col];
#pragma unroll
                for (int j = 0; j < 4; j++) {
                    vt[((size_t)(bidx4[j] * H_ + h) * DH_ + d) * T_ + t4[j]] =
                        f2h((acc[i][j][r] + bs) * mv4[j]);
                }
            }
        }
    }
}

// ---------------------------------------------------------------------------
// Attention R14: REGISTER-ONLY P path. S^T via 16x16x32 (C-layout: lane
// (quad,q=l15) holds keys quad*4+r) -> exp -> pack to half4 == A-operand of
// mfma_f32_16x16x16_f16 (A[m=l15][k=quad*4+j]) -> PV and l-MFMA directly.
// No P LDS, no conflicts, no write->read latency. K/V LDS double-buffer and
// bh-major grid kept from R12. V B-frags (K=16) are b64 reads, <=2-way banks.
// ---------------------------------------------------------------------------
__global__ __launch_bounds__(256) void attn_mfma_kernel(
    const unsigned short* __restrict__ qb,  // [32][2048][64] f16 (pre-scaled)
    const unsigned short* __restrict__ kb,  // [32][2048][64] f16
    const unsigned short* __restrict__ vt,  // [32][64][2048] f16 (mask-zeroed)
    const int* __restrict__ mask,           // [2][2048]
    const unsigned short* __restrict__ mb,  // [2][2048] f16 {0,1}
    float* __restrict__ out)                // [2][2048][1024]
{
    __shared__ unsigned short Ks[2][64 * 64];
    __shared__ unsigned short Vs[2][64 * 64];

    const int bh   = blockIdx.x;            // bh-major: same head -> same XCD
    const int b    = bh >> 4;
    const int h    = bh & 15;
    const int wv   = threadIdx.x >> 6;
    const int lane = threadIdx.x & 63;
    const int l15  = lane & 15;
    const int quad = lane >> 4;
    const int l7   = l15 & 7;
    const int q0w  = blockIdx.y * 128 + wv * 32;

    const unsigned short* kbh = kb + (size_t)bh * T_ * DH_;
    const unsigned short* vbh = vt + (size_t)bh * DH_ * T_;
    const unsigned short* mbb = mb + b * T_;
    const int* __restrict__ mrow = mask + b * T_;

    half8 qf[2][2];
#pragma unroll
    for (int qt = 0; qt < 2; ++qt)
#pragma unroll
        for (int c = 0; c < 2; ++c)
            qf[qt][c] = *(const half8*)(qb + ((size_t)bh * T_ + q0w + qt * 16 + l15) * DH_
                                        + c * 32 + quad * 8);

    f32x4 o[2][4];
#pragma unroll
    for (int qt = 0; qt < 2; ++qt)
#pragma unroll
        for (int n = 0; n < 4; ++n) o[qt][n] = (f32x4){0.f, 0.f, 0.f, 0.f};
    f32x4 lacc[2];
    lacc[0] = (f32x4){0.f, 0.f, 0.f, 0.f};
    lacc[1] = (f32x4){0.f, 0.f, 0.f, 0.f};

    const int lrow = lane >> 3;
    const int gch  = (lane & 7) ^ lrow;

#pragma unroll
    for (int s = 0; s < 4; ++s) {
        int j  = (wv << 2) + s;
        int rb = j & 7;
        if (j < 8) gll16(kbh + (size_t)(rb * 8 + lrow) * DH_ + gch * 8, &Ks[0][rb * 512]);
        else       gll16(vbh + (size_t)(rb * 8 + lrow) * T_  + gch * 8, &Vs[0][rb * 512]);
    }

    for (int kt = 0; kt < 32; ++kt) {
        const int cur   = kt & 1;
        const int kbase = kt * 64;
        __syncthreads();

        if (kt < 31) {
            const int nb = kbase + 64;
#pragma unroll
            for (int s = 0; s < 4; ++s) {
                int j  = (wv << 2) + s;
                int rb = j & 7;
                if (j < 8) gll16(kbh + (size_t)(nb + rb * 8 + lrow) * DH_ + gch * 8,
                                 &Ks[cur ^ 1][rb * 512]);
                else       gll16(vbh + (size_t)(rb * 8 + lrow) * T_ + nb + gch * 8,
                                 &Vs[cur ^ 1][rb * 512]);
            }
        }

        const unsigned short* Kc = &Ks[cur][0];
        const unsigned short* Vc = &Vs[cur][0];

        // K A-frags (16x16x32): K[ktile*16+l15][c*32+quad*8..]
        half8 kf[4][2];
#pragma unroll
        for (int ktile = 0; ktile < 4; ++ktile)
#pragma unroll
            for (int c = 0; c < 2; ++c)
                kf[ktile][c] = *(const half8*)(Kc + (ktile * 16 + l15) * 64
                                               + (((c * 4 + quad) ^ l7) * 8));

        // V B-frags (16x16x16): B[k=quad*4+j][n=l15] -> Vs[n*16+l15][ktile*16+quad*4..+3]
        half4 vb[4][4];   // [n][ktile]
#pragma unroll
        for (int n = 0; n < 4; ++n)
#pragma unroll
            for (int ktile = 0; ktile < 4; ++ktile)
                vb[n][ktile] = *(const half4*)(Vc + (n * 16 + l15) * 64
                                               + (((ktile * 2 + (quad >> 1)) ^ l7) * 8)
                                               + (quad & 1) * 4);

        // mask B-frags (16x16x16, col n=0): keys ktile*16+quad*4..+3
        half4 bmf[4];
#pragma unroll
        for (int ktile = 0; ktile < 4; ++ktile) {
            half4 mv = *(const half4*)(mbb + kbase + ktile * 16 + quad * 4);
            bmf[ktile] = (l15 == 0) ? mv : (half4)0;
        }

#pragma unroll
        for (int qt = 0; qt < 2; ++qt) {
            // S^T -> exp -> in-register A-frags (half4 per ktile)
            half4 pa[4];
#pragma unroll
            for (int ktile = 0; ktile < 4; ++ktile) {
                f32x4 st = (f32x4){0.f, 0.f, 0.f, 0.f};
                st = __builtin_amdgcn_mfma_f32_16x16x32_f16(kf[ktile][0], qf[qt][0], st, 0, 0, 0);
                st = __builtin_amdgcn_mfma_f32_16x16x32_f16(kf[ktile][1], qf[qt][1], st, 0, 0, 0);
                union { uint2 u; half4 h; } cv;
                cv.u.x = pk2(__builtin_amdgcn_exp2f(st[0]), __builtin_amdgcn_exp2f(st[1]));
                cv.u.y = pk2(__builtin_amdgcn_exp2f(st[2]), __builtin_amdgcn_exp2f(st[3]));
                pa[ktile] = cv.h;
            }

            // l += P . maskvec
#pragma unroll
            for (int ktile = 0; ktile < 4; ++ktile)
                lacc[qt] = __builtin_amdgcn_mfma_f32_16x16x16f16(
                    pa[ktile], bmf[ktile], lacc[qt], 0, 0, 0);

            // O += P V
#pragma unroll
            for (int n = 0; n < 4; ++n)
#pragma unroll
                for (int ktile = 0; ktile < 4; ++ktile)
                    o[qt][n] = __builtin_amdgcn_mfma_f32_16x16x16f16(
                        pa[ktile], vb[n][ktile], o[qt][n], 0, 0, 0);
        }
    }

#pragma unroll
    for (int qt = 0; qt < 2; ++qt) {
#pragma unroll
        for (int r = 0; r < 4; ++r) {
            float lv = __shfl(lacc[qt][r], quad << 4, 64);
            int q = q0w + qt * 16 + quad * 4 + r;
            float iv = (mrow[q] != 0 && lv > 0.f) ? (1.0f / lv) : 0.f;
            float* orow = out + ((size_t)(b * T_ + q)) * C_ + h * DH_;
#pragma unroll
            for (int n = 0; n < 4; ++n)
                orow[n * 16 + l15] = o[qt][n][r] * iv;
        }
    }
}

// ---------------------------------------------------------------------------
extern "C" void kernel_launch(void* const* d_in, const int* in_sizes, int n_in,
                              void* d_out, int out_size, void* d_ws, size_t ws_size,
                              hipStream_t stream)
{
    (void)in_sizes; (void)n_in; (void)out_size; (void)ws_size;
    const float* x  = (const float*)d_in[0];
    const float* Wq = (const float*)d_in[1];
    const float* bq = (const float*)d_in[2];
    const float* Wk = (const float*)d_in[3];
    const float* bk = (const float*)d_in[4];
    const float* Wv = (const float*)d_in[5];
    const float* bv = (const float*)d_in[6];
    const int* mask = (const int*)d_in[7];
    float* out = (float*)d_out;

    const size_t NX = (size_t)B_ * T_ * C_;          // 4 Mi elements
    unsigned short* xf = (unsigned short*)d_ws;       // 8 MB fp16 x
    unsigned short* wt = xf + NX;                     // 6 MB fp16 W^T x3
    unsigned short* qb = wt + (size_t)3 * C_ * C_;    // 8 MB (pre-scaled q)
    unsigned short* kb = qb + NX;                     // 8 MB
    unsigned short* vt = kb + NX;                     // 8 MB
    unsigned short* mb = vt + NX;                     // 8 KB

    prep_kernel<<<5120, 256, 0, stream>>>(x, xf, mask, mb, Wq, Wk, Wv, wt);
    qkv_mfma_kernel<<<dim3(32, 8, 3), 256, 0, stream>>>(
        xf, wt, bq, bk, bv, mask, qb, kb, vt);
    attn_mfma_kernel<<<dim3(32, 16), 256, 0, stream>>>(qb, kb, vt, mask, mb, out);
}